// Round 2
// baseline (20949.548 us; speedup 1.0000x reference)
//
#include <hip/hip_runtime.h>
#include <hip/hip_bf16.h>
#include <hip/hip_cooperative_groups.h>
#include <math.h>

namespace cg = cooperative_groups;

// Problem constants
#define T 256
#define B 64
#define FEAT 256
#define HID 1024
#define NCLS 257
#define KTOT 1280          // HID + FEAT
#define NBLK 256           // 1 block per 4 hidden columns
#define NTHR 256           // 4 waves
#define KSTEPS 40          // KTOT / 32

typedef __attribute__((ext_vector_type(8))) short short8v;   // 8 x bf16
typedef __attribute__((ext_vector_type(4))) float floatx4;   // MFMA acc

// Hamilton block component/sign tables
__device__ __constant__ int   d_comp[4][4] = {{0,1,2,3},{1,0,3,2},{2,3,0,1},{3,2,1,0}};
__device__ __constant__ float d_sign[4][4] = {{ 1.f, 1.f, 1.f, 1.f},
                                              {-1.f, 1.f,-1.f, 1.f},
                                              {-1.f, 1.f, 1.f,-1.f},
                                              {-1.f,-1.f, 1.f, 1.f}};

__device__ __forceinline__ ushort f2bf(float f) {
    union { float f; unsigned u; } v; v.f = f;
    unsigned r = v.u + 0x7FFF + ((v.u >> 16) & 1);   // RNE
    return (ushort)(r >> 16);
}

// x (fp32) -> xb (bf16), same [T][B][FEAT] layout
__global__ __launch_bounds__(256) void conv_x(const float* __restrict__ x,
                                              ushort* __restrict__ xb) {
    int i = blockIdx.x * 256 + threadIdx.x;   // over T*B*FEAT/4
    float4 v = ((const float4*)x)[i];
    ushort4 o;
    o.x = f2bf(v.x); o.y = f2bf(v.y); o.z = f2bf(v.z); o.w = f2bf(v.w);
    ((ushort4*)xb)[i] = o;
}

// Persistent cooperative kernel: all 256 LSTM steps.
// Block blk owns hidden columns hid0..hid0+3 (16 gate columns).
// Weights Hamilton-expanded to bf16 MFMA B-fragments in LDS once.
// c state lives in one VGPR per thread for the whole sequence.
__global__ __launch_bounds__(256) void qlstm_persist(
    const ushort* __restrict__ xb,   // [T][B][FEAT] bf16
    const float*  __restrict__ Wh,   // [4][4][256][256]
    const float*  __restrict__ Wx,   // [4][4][64][256]
    const float*  __restrict__ bx,   // [4][1024]
    ushort*       __restrict__ hbuf, // [2][B][HID] bf16 (double-buffered h)
    float*        __restrict__ hs)   // [T][B][HID] fp32
{
    __shared__ __align__(16) ushort fragB[KSTEPS * 64 * 8];  // 40 KB, frag-ordered
    __shared__ float preact[64][20];                         // padded rows

    const int tid  = threadIdx.x;
    const int blk  = blockIdx.x;
    const int hid0 = blk * 4;

    // ---- one-time: build B fragments (Hamilton expansion -> bf16) ----
    // frag element (kstep, lane, j): k = kstep*32 + (lane>>4)*8 + j,
    // local col c = lane&15, c = hl*4 + g  (g = gate, hl = hidden-local)
    for (int e = tid; e < KSTEPS * 64 * 8; e += NTHR) {
        int kstep = e >> 9;
        int r     = e & 511;
        int lane  = r >> 3, j = r & 7;
        int c     = lane & 15;
        int k     = kstep * 32 + ((lane >> 4) << 3) + j;
        int g     = c & 3, hl = c >> 2;
        int n     = hid0 + hl;            // within-gate column 0..1023
        int q     = n >> 8, bc = n & 255;
        float v;
        if (k < HID) {
            int p = k >> 8, a = k & 255;  // Wh row block
            v = d_sign[p][q] * Wh[((g * 4 + d_comp[p][q]) * 256 + a) * 256 + bc];
        } else {
            int kk = k - HID;
            int p = kk >> 6, a = kk & 63; // Wx row block
            v = d_sign[p][q] * Wx[((g * 4 + d_comp[p][q]) * 64 + a) * 256 + bc];
        }
        fragB[e] = f2bf(v);
    }

    // ---- per-thread gate-phase identity: (b, hl) ----
    const int b    = tid >> 2;
    const int hl   = tid & 3;
    const int colg = hid0 + hl;
    hbuf[b * HID + colg] = 0;            // h0 = 0 (buffer 0)
    float c_reg = 0.f;
    const float bf_ = bx[0 * HID + colg];
    const float bi_ = bx[1 * HID + colg];
    const float bo_ = bx[2 * HID + colg];
    const float ba_ = bx[3 * HID + colg];

    // ---- per-thread MFMA identity ----
    const int w    = tid >> 6;           // wave: batch rows 16w..16w+15
    const int lane = tid & 63;
    const int arow = w * 16 + (lane & 15);
    const int kg8  = (lane >> 4) * 8;

    cg::grid_group grid = cg::this_grid();
    __threadfence();
    grid.sync();
    __threadfence();

    const short8v* fb = (const short8v*)fragB;

    for (int t = 0; t < T; ++t) {
        const ushort* hrow = hbuf + (t & 1) * (B * HID) + arow * HID;
        const ushort* xrow = xb + ((size_t)t * B + arow) * FEAT;

        floatx4 acc0 = {0.f, 0.f, 0.f, 0.f};
        floatx4 acc1 = {0.f, 0.f, 0.f, 0.f};
        #pragma unroll
        for (int ks = 0; ks < 32; ks += 2) {
            short8v a0 = *(const short8v*)(hrow + ks * 32 + kg8);
            short8v a1 = *(const short8v*)(hrow + (ks + 1) * 32 + kg8);
            acc0 = __builtin_amdgcn_mfma_f32_16x16x32_bf16(a0, fb[ks * 64 + lane], acc0, 0, 0, 0);
            acc1 = __builtin_amdgcn_mfma_f32_16x16x32_bf16(a1, fb[(ks + 1) * 64 + lane], acc1, 0, 0, 0);
        }
        #pragma unroll
        for (int ks = 32; ks < KSTEPS; ks += 2) {
            short8v a0 = *(const short8v*)(xrow + (ks - 32) * 32 + kg8);
            short8v a1 = *(const short8v*)(xrow + (ks - 31) * 32 + kg8);
            acc0 = __builtin_amdgcn_mfma_f32_16x16x32_bf16(a0, fb[ks * 64 + lane], acc0, 0, 0, 0);
            acc1 = __builtin_amdgcn_mfma_f32_16x16x32_bf16(a1, fb[(ks + 1) * 64 + lane], acc1, 0, 0, 0);
        }
        floatx4 acc = acc0 + acc1;

        // C/D layout: col = lane&15, row = (lane>>4)*4 + j  (within wave's 16 rows)
        #pragma unroll
        for (int j = 0; j < 4; ++j)
            preact[w * 16 + (lane >> 4) * 4 + j][lane & 15] = acc[j];
        __syncthreads();

        float4 pr = *(const float4*)&preact[b][hl * 4];  // f,i,o,a (c = hl*4+g)
        float f  = 1.f / (1.f + __expf(-(pr.x + bf_)));
        float i_ = 1.f / (1.f + __expf(-(pr.y + bi_)));
        float o  = 1.f / (1.f + __expf(-(pr.z + bo_)));
        float a  = pr.w + ba_;
        c_reg = i_ * tanhf(a) + f * c_reg;
        float h = o * tanhf(c_reg);

        hs[(size_t)t * (B * HID) + b * HID + colg] = h;
        hbuf[((t + 1) & 1) * (B * HID) + b * HID + colg] = f2bf(h);

        __threadfence();
        grid.sync();
        __threadfence();
    }
}

// Output projection (fp32, unchanged from round 1): cols 0..255 per block.
__global__ __launch_bounds__(256) void out_gemm(const float* __restrict__ hs,
                                                const float* __restrict__ Wo,
                                                const float* __restrict__ bo,
                                                float* __restrict__ out) {
    __shared__ float hss[32][64];
    const int m0 = blockIdx.x * 32;
    const int tid = threadIdx.x;
    float acc[32];
    float bias = bo[tid];
    #pragma unroll
    for (int m = 0; m < 32; ++m) acc[m] = 0.f;

    const int kkl = tid & 63, mll = tid >> 6;
    for (int k0 = 0; k0 < HID; k0 += 64) {
        #pragma unroll
        for (int r = 0; r < 8; ++r)
            hss[mll + r * 4][kkl] = hs[(m0 + mll + r * 4) * HID + k0 + kkl];
        __syncthreads();
        for (int kk = 0; kk < 64; ++kk) {
            float w = Wo[(k0 + kk) * NCLS + tid];
            #pragma unroll
            for (int m = 0; m < 32; ++m)
                acc[m] += hss[m][kk] * w;
        }
        __syncthreads();
    }
    #pragma unroll
    for (int m = 0; m < 32; ++m)
        out[(m0 + m) * NCLS + tid] = acc[m] + bias;
}

__global__ __launch_bounds__(256) void out_col_last(const float* __restrict__ hs,
                                                    const float* __restrict__ Wo,
                                                    const float* __restrict__ bo,
                                                    float* __restrict__ out) {
    int m = blockIdx.x * 256 + threadIdx.x;
    if (m >= T * B) return;
    float acc = bo[NCLS - 1];
    const float* hr = hs + (size_t)m * HID;
    for (int k = 0; k < HID; k += 4) {
        float4 hv = *(const float4*)&hr[k];
        acc += hv.x * Wo[(k + 0) * NCLS + (NCLS - 1)];
        acc += hv.y * Wo[(k + 1) * NCLS + (NCLS - 1)];
        acc += hv.z * Wo[(k + 2) * NCLS + (NCLS - 1)];
        acc += hv.w * Wo[(k + 3) * NCLS + (NCLS - 1)];
    }
    out[m * NCLS + (NCLS - 1)] = acc;
}

extern "C" void kernel_launch(void* const* d_in, const int* in_sizes, int n_in,
                              void* d_out, int out_size, void* d_ws, size_t ws_size,
                              hipStream_t stream) {
    const float* x  = (const float*)d_in[0];   // [T,B,FEAT]
    const float* Wx = (const float*)d_in[1];   // [4,4,64,256]
    const float* bx = (const float*)d_in[2];   // [4,HID]
    const float* Wh = (const float*)d_in[3];   // [4,4,256,256]
    const float* Wo = (const float*)d_in[4];   // [HID,NCLS]
    const float* bo = (const float*)d_in[5];   // [NCLS]
    float* out = (float*)d_out;

    // Workspace: xb (8 MB bf16) | hbuf (256 KB bf16 x2) | hs (64 MB fp32)
    ushort* xb   = (ushort*)d_ws;
    ushort* hbuf = xb + (size_t)T * B * FEAT;
    float*  hsb  = (float*)(hbuf + 2 * B * HID);

    conv_x<<<(T * B * FEAT / 4) / 256, 256, 0, stream>>>(x, xb);

    void* args[] = {(void*)&xb, (void*)&Wh, (void*)&Wx, (void*)&bx,
                    (void*)&hbuf, (void*)&hsb};
    hipLaunchCooperativeKernel((void*)qlstm_persist, dim3(NBLK), dim3(NTHR),
                               args, 0, stream);

    out_gemm<<<(T * B) / 32, 256, 0, stream>>>(hsb, Wo, bo, out);
    out_col_last<<<(T * B) / 256, 256, 0, stream>>>(hsb, Wo, bo, out);
}

// Round 3
// 2371.375 us; speedup vs baseline: 8.8343x; 8.8343x over previous
//
#include <hip/hip_runtime.h>
#include <hip/hip_bf16.h>
#include <math.h>

// Problem constants
#define T 256
#define B 64
#define FEAT 256
#define HID 1024
#define NCLS 257
#define KTOT 1280          // HID + FEAT
#define NG 4096            // 4 gates * HID
#define KSTEPS 40          // KTOT / 32
#define BH (B * HID)

typedef __attribute__((ext_vector_type(8))) short short8v;   // 8 x bf16
typedef __attribute__((ext_vector_type(4))) float floatx4;   // MFMA acc

// Hamilton block component/sign tables
__device__ __constant__ int   d_comp[4][4] = {{0,1,2,3},{1,0,3,2},{2,3,0,1},{3,2,1,0}};
__device__ __constant__ float d_sign[4][4] = {{ 1.f, 1.f, 1.f, 1.f},
                                              {-1.f, 1.f,-1.f, 1.f},
                                              {-1.f, 1.f, 1.f,-1.f},
                                              {-1.f,-1.f, 1.f, 1.f}};

__device__ __forceinline__ ushort f2bf(float f) {
    union { float f; unsigned u; } v; v.f = f;
    unsigned r = v.u + 0x7FFF + ((v.u >> 16) & 1);   // RNE
    return (ushort)(r >> 16);
}

// x (fp32) -> xb (bf16), same [T][B][FEAT] layout
__global__ __launch_bounds__(256) void conv_x(const float* __restrict__ x,
                                              ushort* __restrict__ xb) {
    int i = blockIdx.x * 256 + threadIdx.x;   // over T*B*FEAT/4
    float4 v = ((const float4*)x)[i];
    ushort4 o;
    o.x = f2bf(v.x); o.y = f2bf(v.y); o.z = f2bf(v.z); o.w = f2bf(v.w);
    ((ushort4*)xb)[i] = o;
}

// Build frag-ordered bf16 combined weights:
// wcf element e = ((blk*40 + ks)*64 + lane)*8 + j
//   local gate col c = lane&15 -> hl = c>>2, g = c&3; hidden col n = blk*4+hl
//   k = ks*32 + (lane>>4)*8 + j   (k<1024: Wh rows, else Wx rows)
__global__ __launch_bounds__(256) void prep_wcf(const float* __restrict__ Wh,
                                                const float* __restrict__ Wx,
                                                ushort* __restrict__ wcf) {
    int e = blockIdx.x * 256 + threadIdx.x;   // < 256*40*512 = 5,242,880
    int j    = e & 7;
    int lane = (e >> 3) & 63;
    int q40  = e >> 9;
    int blk  = q40 / 40;
    int ks   = q40 - blk * 40;
    int c  = lane & 15;
    int hl = c >> 2, g = c & 3;
    int n  = blk * 4 + hl;
    int qq = n >> 8, bc = n & 255;
    int k  = ks * 32 + ((lane >> 4) << 3) + j;
    float v;
    if (k < HID) {
        int p = k >> 8, a = k & 255;
        v = d_sign[p][qq] * Wh[((g * 4 + d_comp[p][qq]) * 256 + a) * 256 + bc];
    } else {
        int kk = k - HID;
        int p = kk >> 6, a = kk & 63;
        v = d_sign[p][qq] * Wx[((g * 4 + d_comp[p][qq]) * 64 + a) * 256 + bc];
    }
    wcf[e] = f2bf(v);
}

// Wo -> frag-ordered bf16, cols padded to 320:
// e = ((tile*32 + ks)*64 + lane)*8 + j ; n = tile*16 + (lane&15)
__global__ __launch_bounds__(256) void prep_wof(const float* __restrict__ Wo,
                                                ushort* __restrict__ wof) {
    int e = blockIdx.x * 256 + threadIdx.x;   // < 20*32*512 = 327,680
    int j    = e & 7;
    int lane = (e >> 3) & 63;
    int ks   = (e >> 9) & 31;
    int tile = e >> 14;
    int n = tile * 16 + (lane & 15);
    int k = ks * 32 + ((lane >> 4) << 3) + j;
    wof[e] = (n < NCLS) ? f2bf(Wo[k * NCLS + n]) : (ushort)0;
}

// zero h0 (buffer 0) and c
__global__ __launch_bounds__(256) void init_hc(ushort* __restrict__ hbuf,
                                               float* __restrict__ cbuf) {
    int i = blockIdx.x * 256 + threadIdx.x;   // over BH
    hbuf[i] = 0;
    cbuf[i] = 0.f;
}

// One LSTM step, fully fused: block blk owns hidden cols blk*4..blk*4+3
// (16 gate cols). 4 waves, wave w computes batch rows 16w..16w+15.
__global__ __launch_bounds__(256) void step_kernel(
    const ushort* __restrict__ xb,    // [T][B][FEAT] bf16
    const ushort* __restrict__ wcf,   // frag-ordered weights
    const float*  __restrict__ bx,    // [4][1024]
    ushort*       __restrict__ hbuf,  // [2][B][HID] bf16
    float*        __restrict__ cbuf,  // [B][HID] fp32
    ushort*       __restrict__ hsb,   // [T][B][HID] bf16
    int t)
{
    __shared__ float preact[64][20];
    const int tid  = threadIdx.x;
    const int blk  = blockIdx.x;
    const int w    = tid >> 6;
    const int lane = tid & 63;
    const int row  = w * 16 + (lane & 15);
    const int kg8  = (lane >> 4) * 8;

    const ushort* hrow = hbuf + (t & 1) * BH + row * HID + kg8;
    const ushort* xrow = xb + ((size_t)t * B + row) * FEAT + kg8;
    const short8v* wb  = (const short8v*)wcf + (size_t)blk * KSTEPS * 64;

    floatx4 ac0 = {0.f,0.f,0.f,0.f}, ac1 = {0.f,0.f,0.f,0.f};
    floatx4 ac2 = {0.f,0.f,0.f,0.f}, ac3 = {0.f,0.f,0.f,0.f};

    #pragma unroll
    for (int ks = 0; ks < 32; ks += 4) {
        short8v a0 = *(const short8v*)(hrow + (ks + 0) * 32);
        short8v a1 = *(const short8v*)(hrow + (ks + 1) * 32);
        short8v a2 = *(const short8v*)(hrow + (ks + 2) * 32);
        short8v a3 = *(const short8v*)(hrow + (ks + 3) * 32);
        ac0 = __builtin_amdgcn_mfma_f32_16x16x32_bf16(a0, wb[(ks + 0) * 64 + lane], ac0, 0, 0, 0);
        ac1 = __builtin_amdgcn_mfma_f32_16x16x32_bf16(a1, wb[(ks + 1) * 64 + lane], ac1, 0, 0, 0);
        ac2 = __builtin_amdgcn_mfma_f32_16x16x32_bf16(a2, wb[(ks + 2) * 64 + lane], ac2, 0, 0, 0);
        ac3 = __builtin_amdgcn_mfma_f32_16x16x32_bf16(a3, wb[(ks + 3) * 64 + lane], ac3, 0, 0, 0);
    }
    #pragma unroll
    for (int u = 0; u < 8; u += 4) {
        short8v a0 = *(const short8v*)(xrow + (u + 0) * 32);
        short8v a1 = *(const short8v*)(xrow + (u + 1) * 32);
        short8v a2 = *(const short8v*)(xrow + (u + 2) * 32);
        short8v a3 = *(const short8v*)(xrow + (u + 3) * 32);
        ac0 = __builtin_amdgcn_mfma_f32_16x16x32_bf16(a0, wb[(32 + u + 0) * 64 + lane], ac0, 0, 0, 0);
        ac1 = __builtin_amdgcn_mfma_f32_16x16x32_bf16(a1, wb[(32 + u + 1) * 64 + lane], ac1, 0, 0, 0);
        ac2 = __builtin_amdgcn_mfma_f32_16x16x32_bf16(a2, wb[(32 + u + 2) * 64 + lane], ac2, 0, 0, 0);
        ac3 = __builtin_amdgcn_mfma_f32_16x16x32_bf16(a3, wb[(32 + u + 3) * 64 + lane], ac3, 0, 0, 0);
    }
    floatx4 acc = (ac0 + ac1) + (ac2 + ac3);

    // C/D layout: col = lane&15, row = (lane>>4)*4 + j
    #pragma unroll
    for (int j = 0; j < 4; ++j)
        preact[w * 16 + (lane >> 4) * 4 + j][lane & 15] = acc[j];
    __syncthreads();

    // gate phase: thread -> (b = tid>>2, hl = tid&3)
    const int b  = tid >> 2;
    const int hl = tid & 3;
    const int n  = blk * 4 + hl;
    float4 pr = *(const float4*)&preact[b][hl * 4];    // f,i,o,a
    float f  = 1.f / (1.f + __expf(-(pr.x + bx[n])));
    float i_ = 1.f / (1.f + __expf(-(pr.y + bx[HID + n])));
    float o  = 1.f / (1.f + __expf(-(pr.z + bx[2 * HID + n])));
    float a  = pr.w + bx[3 * HID + n];
    const int ci = b * HID + n;
    float cn = i_ * tanhf(a) + f * cbuf[ci];
    cbuf[ci] = cn;
    ushort hb = f2bf(o * tanhf(cn));
    hsb[(size_t)t * BH + ci] = hb;
    hbuf[((t + 1) & 1) * BH + ci] = hb;
}

// Output projection via MFMA: block (mtile, nt) computes rows m0..m0+63,
// cols nt*64..nt*64+63 (masked to 257). K = HID.
__global__ __launch_bounds__(256) void outproj(const ushort* __restrict__ hsb,
                                               const ushort* __restrict__ wof,
                                               const float* __restrict__ bo,
                                               float* __restrict__ out) {
    const int m0   = blockIdx.x * 64;
    const int nt   = blockIdx.y;          // 0..4
    const int tid  = threadIdx.x;
    const int w    = tid >> 6;
    const int lane = tid & 63;
    const int kg8  = (lane >> 4) * 8;
    const ushort* arow = hsb + (size_t)(m0 + w * 16 + (lane & 15)) * HID + kg8;
    const short8v* wb  = (const short8v*)wof;

    floatx4 ac[4] = {{0.f,0.f,0.f,0.f},{0.f,0.f,0.f,0.f},
                     {0.f,0.f,0.f,0.f},{0.f,0.f,0.f,0.f}};
    #pragma unroll 4
    for (int ks = 0; ks < 32; ++ks) {
        short8v av = *(const short8v*)(arow + ks * 32);
        #pragma unroll
        for (int ct = 0; ct < 4; ++ct)
            ac[ct] = __builtin_amdgcn_mfma_f32_16x16x32_bf16(
                av, wb[((nt * 4 + ct) * 32 + ks) * 64 + lane], ac[ct], 0, 0, 0);
    }
    const int orow = m0 + w * 16 + (lane >> 4) * 4;
    #pragma unroll
    for (int ct = 0; ct < 4; ++ct) {
        int n = nt * 64 + ct * 16 + (lane & 15);
        if (n < NCLS) {
            float bias = bo[n];
            #pragma unroll
            for (int j = 0; j < 4; ++j)
                out[(size_t)(orow + j) * NCLS + n] = ac[ct][j] + bias;
        }
    }
}

extern "C" void kernel_launch(void* const* d_in, const int* in_sizes, int n_in,
                              void* d_out, int out_size, void* d_ws, size_t ws_size,
                              hipStream_t stream) {
    const float* x  = (const float*)d_in[0];   // [T,B,FEAT]
    const float* Wx = (const float*)d_in[1];   // [4,4,64,256]
    const float* bx = (const float*)d_in[2];   // [4,HID]
    const float* Wh = (const float*)d_in[3];   // [4,4,256,256]
    const float* Wo = (const float*)d_in[4];   // [HID,NCLS]
    const float* bo = (const float*)d_in[5];   // [NCLS]
    float* out = (float*)d_out;

    // Workspace layout (ushort units unless noted), total ~53.6 MB
    ushort* xb   = (ushort*)d_ws;              // 4,194,304
    ushort* wcf  = xb   + (size_t)T * B * FEAT;        // 5,242,880
    ushort* wof  = wcf  + (size_t)KSTEPS * 256 * 512;  // 327,680
    ushort* hbuf = wof  + 327680;                      // 131,072
    ushort* hsb  = hbuf + 2 * BH;                      // 16,777,216
    float*  cbuf = (float*)(hsb + (size_t)T * BH);     // 65,536 floats

    conv_x<<<(T * B * FEAT / 4) / 256, 256, 0, stream>>>(x, xb);
    prep_wcf<<<(256 * KSTEPS * 512) / 256, 256, 0, stream>>>(Wh, Wx, wcf);
    prep_wof<<<(20 * 32 * 512) / 256, 256, 0, stream>>>(Wo, wof);
    init_hc<<<BH / 256, 256, 0, stream>>>(hbuf, cbuf);

    for (int t = 0; t < T; ++t)
        step_kernel<<<256, 256, 0, stream>>>(xb, wcf, bx, hbuf, cbuf, hsb, t);

    outproj<<<dim3(T * B / 64, 5), 256, 0, stream>>>(hsb, wof, bo, out);
}

// Round 4
// 2236.839 us; speedup vs baseline: 9.3657x; 1.0601x over previous
//
#include <hip/hip_runtime.h>
#include <hip/hip_bf16.h>
#include <math.h>

// Problem constants
#define T 256
#define B 64
#define FEAT 256
#define HID 1024
#define NCLS 257
#define KTOT 1280          // HID + FEAT
#define KSTEPS 40          // KTOT / 32
#define KH 20              // ksteps per K-half
#define BH (B * HID)

typedef __attribute__((ext_vector_type(8))) short short8v;   // 8 x bf16
typedef __attribute__((ext_vector_type(4))) float floatx4;   // MFMA acc

// Hamilton block component/sign tables
__device__ __constant__ int   d_comp[4][4] = {{0,1,2,3},{1,0,3,2},{2,3,0,1},{3,2,1,0}};
__device__ __constant__ float d_sign[4][4] = {{ 1.f, 1.f, 1.f, 1.f},
                                              {-1.f, 1.f,-1.f, 1.f},
                                              {-1.f, 1.f, 1.f,-1.f},
                                              {-1.f,-1.f, 1.f, 1.f}};

__device__ __forceinline__ ushort f2bf(float f) {
    union { float f; unsigned u; } v; v.f = f;
    unsigned r = v.u + 0x7FFF + ((v.u >> 16) & 1);   // RNE
    return (ushort)(r >> 16);
}

// x (fp32) -> xb (bf16), same [T][B][FEAT] layout
__global__ __launch_bounds__(256) void conv_x(const float* __restrict__ x,
                                              ushort* __restrict__ xb) {
    int i = blockIdx.x * 256 + threadIdx.x;   // over T*B*FEAT/4
    float4 v = ((const float4*)x)[i];
    ushort4 o;
    o.x = f2bf(v.x); o.y = f2bf(v.y); o.z = f2bf(v.z); o.w = f2bf(v.w);
    ((ushort4*)xb)[i] = o;
}

// Build frag-ordered bf16 combined weights:
// wcf element e = ((blk*40 + ks)*64 + lane)*8 + j
//   local gate col c = lane&15 -> hl = c>>2, g = c&3; hidden col n = blk*4+hl
//   k = ks*32 + (lane>>4)*8 + j   (k<1024: Wh rows, else Wx rows)
__global__ __launch_bounds__(256) void prep_wcf(const float* __restrict__ Wh,
                                                const float* __restrict__ Wx,
                                                ushort* __restrict__ wcf) {
    int e = blockIdx.x * 256 + threadIdx.x;   // < 256*40*512 = 5,242,880
    int j    = e & 7;
    int lane = (e >> 3) & 63;
    int q40  = e >> 9;
    int blk  = q40 / 40;
    int ks   = q40 - blk * 40;
    int c  = lane & 15;
    int hl = c >> 2, g = c & 3;
    int n  = blk * 4 + hl;
    int qq = n >> 8, bc = n & 255;
    int k  = ks * 32 + ((lane >> 4) << 3) + j;
    float v;
    if (k < HID) {
        int p = k >> 8, a = k & 255;
        v = d_sign[p][qq] * Wh[((g * 4 + d_comp[p][qq]) * 256 + a) * 256 + bc];
    } else {
        int kk = k - HID;
        int p = kk >> 6, a = kk & 63;
        v = d_sign[p][qq] * Wx[((g * 4 + d_comp[p][qq]) * 64 + a) * 256 + bc];
    }
    wcf[e] = f2bf(v);
}

// Wo -> frag-ordered bf16, cols padded to 320:
// e = ((tile*32 + ks)*64 + lane)*8 + j ; n = tile*16 + (lane&15)
__global__ __launch_bounds__(256) void prep_wof(const float* __restrict__ Wo,
                                                ushort* __restrict__ wof) {
    int e = blockIdx.x * 256 + threadIdx.x;   // < 20*32*512 = 327,680
    int j    = e & 7;
    int lane = (e >> 3) & 63;
    int ks   = (e >> 9) & 31;
    int tile = e >> 14;
    int n = tile * 16 + (lane & 15);
    int k = ks * 32 + ((lane >> 4) << 3) + j;
    wof[e] = (n < NCLS) ? f2bf(Wo[k * NCLS + n]) : (ushort)0;
}

// zero h0 (buffer 0) and c
__global__ __launch_bounds__(256) void init_hc(ushort* __restrict__ hbuf,
                                               float* __restrict__ cbuf) {
    int i = blockIdx.x * 256 + threadIdx.x;   // over BH
    hbuf[i] = 0;
    cbuf[i] = 0.f;
}

// One LSTM step, fully fused. Block blk owns hidden cols blk*4..blk*4+3
// (16 gate cols). 512 threads = 8 waves: wave w -> (khalf = w>>2 of the
// K range, quad = w&3 -> batch rows quad*16..quad*16+15). B-frags staged
// in LDS once (40 KB) and shared by all waves; K-half partials reduced
// through LDS preact in the gate phase.
__global__ __launch_bounds__(512) void step_kernel(
    const ushort* __restrict__ xb,    // [T][B][FEAT] bf16
    const ushort* __restrict__ wcf,   // frag-ordered weights
    const float*  __restrict__ bx,    // [4][1024]
    ushort*       __restrict__ hbuf,  // [2][B][HID] bf16
    float*        __restrict__ cbuf,  // [B][HID] fp32
    ushort*       __restrict__ hsb,   // [T][B][HID] bf16
    int t)
{
    __shared__ __align__(16) ushort fragB[KSTEPS * 512];  // 40 KB
    __shared__ float pre[2][64][20];                      // K-half partials

    const int tid   = threadIdx.x;
    const int blk   = blockIdx.x;
    const int w     = tid >> 6;
    const int lane  = tid & 63;
    const int khalf = w >> 2;
    const int quad  = w & 3;
    const int row   = quad * 16 + (lane & 15);
    const int kg8   = (lane >> 4) * 8;

    // ---- stage B-frags into LDS (coalesced, ds_write_b128) ----
    {
        const short8v* wsrc = (const short8v*)(wcf + (size_t)blk * KSTEPS * 512);
        short8v* wdst = (short8v*)fragB;
        #pragma unroll
        for (int i = 0; i < 5; ++i)
            wdst[i * 512 + tid] = wsrc[i * 512 + tid];
    }

    const ushort* hrow = hbuf + (t & 1) * BH + row * HID + kg8;
    const ushort* xrow = xb + ((size_t)t * B + row) * FEAT + kg8;

    __syncthreads();

    const short8v* fb = (const short8v*)fragB + (size_t)khalf * KH * 64 + lane;

    floatx4 ac0 = {0.f,0.f,0.f,0.f}, ac1 = {0.f,0.f,0.f,0.f};
    floatx4 ac2 = {0.f,0.f,0.f,0.f}, ac3 = {0.f,0.f,0.f,0.f};

    if (khalf == 0) {
        // absolute ksteps 0..19, all from h
        #pragma unroll
        for (int i = 0; i < KH; i += 4) {
            short8v a0 = *(const short8v*)(hrow + (i + 0) * 32);
            short8v a1 = *(const short8v*)(hrow + (i + 1) * 32);
            short8v a2 = *(const short8v*)(hrow + (i + 2) * 32);
            short8v a3 = *(const short8v*)(hrow + (i + 3) * 32);
            ac0 = __builtin_amdgcn_mfma_f32_16x16x32_bf16(a0, fb[(i + 0) * 64], ac0, 0, 0, 0);
            ac1 = __builtin_amdgcn_mfma_f32_16x16x32_bf16(a1, fb[(i + 1) * 64], ac1, 0, 0, 0);
            ac2 = __builtin_amdgcn_mfma_f32_16x16x32_bf16(a2, fb[(i + 2) * 64], ac2, 0, 0, 0);
            ac3 = __builtin_amdgcn_mfma_f32_16x16x32_bf16(a3, fb[(i + 3) * 64], ac3, 0, 0, 0);
        }
    } else {
        // absolute ksteps 20..31 from h (local 0..11), 32..39 from x (local 12..19)
        #pragma unroll
        for (int i = 0; i < 12; i += 4) {
            short8v a0 = *(const short8v*)(hrow + (20 + i + 0) * 32);
            short8v a1 = *(const short8v*)(hrow + (20 + i + 1) * 32);
            short8v a2 = *(const short8v*)(hrow + (20 + i + 2) * 32);
            short8v a3 = *(const short8v*)(hrow + (20 + i + 3) * 32);
            ac0 = __builtin_amdgcn_mfma_f32_16x16x32_bf16(a0, fb[(i + 0) * 64], ac0, 0, 0, 0);
            ac1 = __builtin_amdgcn_mfma_f32_16x16x32_bf16(a1, fb[(i + 1) * 64], ac1, 0, 0, 0);
            ac2 = __builtin_amdgcn_mfma_f32_16x16x32_bf16(a2, fb[(i + 2) * 64], ac2, 0, 0, 0);
            ac3 = __builtin_amdgcn_mfma_f32_16x16x32_bf16(a3, fb[(i + 3) * 64], ac3, 0, 0, 0);
        }
        #pragma unroll
        for (int i = 12; i < KH; i += 4) {
            short8v a0 = *(const short8v*)(xrow + (i - 12 + 0) * 32);
            short8v a1 = *(const short8v*)(xrow + (i - 12 + 1) * 32);
            short8v a2 = *(const short8v*)(xrow + (i - 12 + 2) * 32);
            short8v a3 = *(const short8v*)(xrow + (i - 12 + 3) * 32);
            ac0 = __builtin_amdgcn_mfma_f32_16x16x32_bf16(a0, fb[(i + 0) * 64], ac0, 0, 0, 0);
            ac1 = __builtin_amdgcn_mfma_f32_16x16x32_bf16(a1, fb[(i + 1) * 64], ac1, 0, 0, 0);
            ac2 = __builtin_amdgcn_mfma_f32_16x16x32_bf16(a2, fb[(i + 2) * 64], ac2, 0, 0, 0);
            ac3 = __builtin_amdgcn_mfma_f32_16x16x32_bf16(a3, fb[(i + 3) * 64], ac3, 0, 0, 0);
        }
    }
    floatx4 acc = (ac0 + ac1) + (ac2 + ac3);

    // C/D layout: col = lane&15, row = (lane>>4)*4 + j
    #pragma unroll
    for (int j = 0; j < 4; ++j)
        pre[khalf][quad * 16 + (lane >> 4) * 4 + j][lane & 15] = acc[j];
    __syncthreads();

    // gate phase: first 256 threads -> (b = tid>>2, hl = tid&3)
    if (tid < 256) {
        const int b  = tid >> 2;
        const int hl = tid & 3;
        const int n  = blk * 4 + hl;
        float4 p0 = *(const float4*)&pre[0][b][hl * 4];
        float4 p1 = *(const float4*)&pre[1][b][hl * 4];
        float f  = 1.f / (1.f + __expf(-(p0.x + p1.x + bx[n])));
        float i_ = 1.f / (1.f + __expf(-(p0.y + p1.y + bx[HID + n])));
        float o  = 1.f / (1.f + __expf(-(p0.z + p1.z + bx[2 * HID + n])));
        float a  = p0.w + p1.w + bx[3 * HID + n];
        const int ci = b * HID + n;
        float cn = i_ * tanhf(a) + f * cbuf[ci];
        cbuf[ci] = cn;
        ushort hb = f2bf(o * tanhf(cn));
        hsb[(size_t)t * BH + ci] = hb;
        hbuf[((t + 1) & 1) * BH + ci] = hb;
    }
}

// Output projection via MFMA: block (mtile, nt) computes rows m0..m0+63,
// cols nt*64..nt*64+63 (masked to 257). K = HID.
__global__ __launch_bounds__(256) void outproj(const ushort* __restrict__ hsb,
                                               const ushort* __restrict__ wof,
                                               const float* __restrict__ bo,
                                               float* __restrict__ out) {
    const int m0   = blockIdx.x * 64;
    const int nt   = blockIdx.y;          // 0..4
    const int tid  = threadIdx.x;
    const int w    = tid >> 6;
    const int lane = tid & 63;
    const int kg8  = (lane >> 4) * 8;
    const ushort* arow = hsb + (size_t)(m0 + w * 16 + (lane & 15)) * HID + kg8;
    const short8v* wb  = (const short8v*)wof;

    floatx4 ac[4] = {{0.f,0.f,0.f,0.f},{0.f,0.f,0.f,0.f},
                     {0.f,0.f,0.f,0.f},{0.f,0.f,0.f,0.f}};
    #pragma unroll 4
    for (int ks = 0; ks < 32; ++ks) {
        short8v av = *(const short8v*)(arow + ks * 32);
        #pragma unroll
        for (int ct = 0; ct < 4; ++ct)
            ac[ct] = __builtin_amdgcn_mfma_f32_16x16x32_bf16(
                av, wb[((nt * 4 + ct) * 32 + ks) * 64 + lane], ac[ct], 0, 0, 0);
    }
    const int orow = m0 + w * 16 + (lane >> 4) * 4;
    #pragma unroll
    for (int ct = 0; ct < 4; ++ct) {
        int n = nt * 64 + ct * 16 + (lane & 15);
        if (n < NCLS) {
            float bias = bo[n];
            #pragma unroll
            for (int j = 0; j < 4; ++j)
                out[(size_t)(orow + j) * NCLS + n] = ac[ct][j] + bias;
        }
    }
}

extern "C" void kernel_launch(void* const* d_in, const int* in_sizes, int n_in,
                              void* d_out, int out_size, void* d_ws, size_t ws_size,
                              hipStream_t stream) {
    const float* x  = (const float*)d_in[0];   // [T,B,FEAT]
    const float* Wx = (const float*)d_in[1];   // [4,4,64,256]
    const float* bx = (const float*)d_in[2];   // [4,HID]
    const float* Wh = (const float*)d_in[3];   // [4,4,256,256]
    const float* Wo = (const float*)d_in[4];   // [HID,NCLS]
    const float* bo = (const float*)d_in[5];   // [NCLS]
    float* out = (float*)d_out;

    // Workspace layout (ushort units unless noted), total ~53.6 MB
    ushort* xb   = (ushort*)d_ws;                      // 4,194,304
    ushort* wcf  = xb   + (size_t)T * B * FEAT;        // 5,242,880
    ushort* wof  = wcf  + (size_t)KSTEPS * 256 * 512;  // 327,680
    ushort* hbuf = wof  + 327680;                      // 131,072
    ushort* hsb  = hbuf + 2 * BH;                      // 16,777,216
    float*  cbuf = (float*)(hsb + (size_t)T * BH);     // 65,536 floats

    conv_x<<<(T * B * FEAT / 4) / 256, 256, 0, stream>>>(x, xb);
    prep_wcf<<<(256 * KSTEPS * 512) / 256, 256, 0, stream>>>(Wh, Wx, wcf);
    prep_wof<<<(20 * 32 * 512) / 256, 256, 0, stream>>>(Wo, wof);
    init_hc<<<BH / 256, 256, 0, stream>>>(hbuf, cbuf);

    for (int t = 0; t < T; ++t)
        step_kernel<<<256, 512, 0, stream>>>(xb, wcf, bx, hbuf, cbuf, hsb, t);

    outproj<<<dim3(T * B / 64, 5), 256, 0, stream>>>(hsb, wof, bo, out);
}

// Round 5
// 2171.319 us; speedup vs baseline: 9.6483x; 1.0302x over previous
//
#include <hip/hip_runtime.h>
#include <hip/hip_bf16.h>
#include <math.h>

// Problem constants
#define T 256
#define B 64
#define FEAT 256
#define HID 1024
#define NCLS 257
#define KSTEPS 40          // K = 1280 = 40 * 32
#define BH (B * HID)
#define NBLK 256
#define NTHR 512

typedef __attribute__((ext_vector_type(8))) short short8v;   // 8 x bf16
typedef __attribute__((ext_vector_type(4))) float floatx4;   // MFMA acc

// Hamilton block component/sign tables
__device__ __constant__ int   d_comp[4][4] = {{0,1,2,3},{1,0,3,2},{2,3,0,1},{3,2,1,0}};
__device__ __constant__ float d_sign[4][4] = {{ 1.f, 1.f, 1.f, 1.f},
                                              {-1.f, 1.f,-1.f, 1.f},
                                              {-1.f, 1.f, 1.f,-1.f},
                                              {-1.f,-1.f, 1.f, 1.f}};

__device__ __forceinline__ ushort f2bf(float f) {
    union { float f; unsigned u; } v; v.f = f;
    unsigned r = v.u + 0x7FFF + ((v.u >> 16) & 1);   // RNE
    return (ushort)(r >> 16);
}

__device__ __forceinline__ float sigm(float v) { return 1.f / (1.f + __expf(-v)); }
__device__ __forceinline__ float tanh_fast(float v) { return 1.f - 2.f / (1.f + __expf(2.f * v)); }

// x (fp32) -> xb (bf16), same [T][B][FEAT] layout
__global__ __launch_bounds__(256) void conv_x(const float* __restrict__ x,
                                              ushort* __restrict__ xb) {
    int i = blockIdx.x * 256 + threadIdx.x;   // over T*B*FEAT/4
    float4 v = ((const float4*)x)[i];
    ushort4 o;
    o.x = f2bf(v.x); o.y = f2bf(v.y); o.z = f2bf(v.z); o.w = f2bf(v.w);
    ((ushort4*)xb)[i] = o;
}

// Build frag-ordered bf16 combined weights:
// wcf element e = ((blk*40 + ks)*64 + lane)*8 + j
//   gate col c = lane&15 -> hl = c>>2, g = c&3; hidden col n = blk*4+hl
//   k = ks*32 + (lane>>4)*8 + j   (k<1024: Wh rows, else Wx rows)
__global__ __launch_bounds__(256) void prep_wcf(const float* __restrict__ Wh,
                                                const float* __restrict__ Wx,
                                                ushort* __restrict__ wcf) {
    int e = blockIdx.x * 256 + threadIdx.x;   // < 256*40*512 = 5,242,880
    int j    = e & 7;
    int lane = (e >> 3) & 63;
    int q40  = e >> 9;
    int blk  = q40 / 40;
    int ks   = q40 - blk * 40;
    int c  = lane & 15;
    int hl = c >> 2, g = c & 3;
    int n  = blk * 4 + hl;
    int qq = n >> 8, bc = n & 255;
    int k  = ks * 32 + ((lane >> 4) << 3) + j;
    float v;
    if (k < HID) {
        int p = k >> 8, a = k & 255;
        v = d_sign[p][qq] * Wh[((g * 4 + d_comp[p][qq]) * 256 + a) * 256 + bc];
    } else {
        int kk = k - HID;
        int p = kk >> 6, a = kk & 63;
        v = d_sign[p][qq] * Wx[((g * 4 + d_comp[p][qq]) * 64 + a) * 256 + bc];
    }
    wcf[e] = f2bf(v);
}

// Wo -> frag-ordered bf16, cols padded to 320
__global__ __launch_bounds__(256) void prep_wof(const float* __restrict__ Wo,
                                                ushort* __restrict__ wof) {
    int e = blockIdx.x * 256 + threadIdx.x;   // < 20*32*512 = 327,680
    int j    = e & 7;
    int lane = (e >> 3) & 63;
    int ks   = (e >> 9) & 31;
    int tile = e >> 14;
    int n = tile * 16 + (lane & 15);
    int k = ks * 32 + ((lane >> 4) << 3) + j;
    wof[e] = (n < NCLS) ? f2bf(Wo[k * NCLS + n]) : (ushort)0;
}

// zero h slot 0 and the barrier counter
__global__ __launch_bounds__(256) void init_hc(ushort* __restrict__ hs0,
                                               uint* __restrict__ bar) {
    int i = blockIdx.x * 256 + threadIdx.x;   // over BH
    hs0[i] = 0;
    if (i == 0) *bar = 0;
}

// Persistent kernel: all 256 LSTM steps, custom MALL barrier (no fences).
// Block blk owns hidden cols blk*4..blk*4+3 (16 gate cols). 8 waves:
// khalf = w>>2 splits K, quad = w&3 -> batch rows quad*16..+15.
// All 20 B-fragments live in registers for the whole sequence.
__global__ __launch_bounds__(512, 2) void qlstm_persist(
    const ushort* __restrict__ xb,     // [T][B][FEAT] bf16
    const ushort* __restrict__ wcf,    // frag-ordered weights
    const float*  __restrict__ bx,     // [4][1024]
    ushort*       __restrict__ hsteps, // [T+1][B][HID] bf16 (slot s = h after s steps)
    uint*         __restrict__ bar)    // barrier counter (MALL)
{
    __shared__ float pre[2][64][20];

    const int tid   = threadIdx.x;
    const int blk   = blockIdx.x;
    const int w     = tid >> 6;
    const int lane  = tid & 63;
    const int khalf = w >> 2;
    const int quad  = w & 3;
    const int rowoff = (quad * 16 + (lane & 15)) * HID + (lane >> 4) * 8;
    const int xrowoff = (quad * 16 + (lane & 15)) * FEAT + (lane >> 4) * 8;
    const int hofs  = khalf * 16;   // h ksteps: 0..15 or 16..31
    const int xofs  = khalf * 4;    // x ksteps (local): 0..3 or 4..7

    // ---- one-time: B-fragments -> registers (160 VGPRs) ----
    const short8v* wsrc = (const short8v*)(wcf + (size_t)blk * KSTEPS * 512);
    short8v bh[16], bxr[4];
    #pragma unroll
    for (int i = 0; i < 16; ++i) bh[i] = wsrc[(hofs + i) * 64 + lane];
    #pragma unroll
    for (int u = 0; u < 4; ++u)  bxr[u] = wsrc[(32 + xofs + u) * 64 + lane];

    // ---- gate-phase identity (threads 0..255): (b, hl) ----
    const int gb = tid >> 2;
    const int hl = tid & 3;
    const int gn = blk * 4 + hl;
    float bxf = 0.f, bxi = 0.f, bxo = 0.f, bxa = 0.f;
    if (tid < 256) {
        bxf = bx[gn]; bxi = bx[HID + gn];
        bxo = bx[2 * HID + gn]; bxa = bx[3 * HID + gn];
    }
    float c_reg = 0.f;

    for (int t = 0; t < T; ++t) {
        const ushort* hrow = hsteps + (size_t)t * BH + rowoff;
        const ushort* xrow = xb + (size_t)t * (B * FEAT) + xrowoff;

        floatx4 ac0 = {0.f,0.f,0.f,0.f}, ac1 = {0.f,0.f,0.f,0.f};
        floatx4 ac2 = {0.f,0.f,0.f,0.f}, ac3 = {0.f,0.f,0.f,0.f};

        // x-part (independent of this step's h) — overlaps barrier wait
        {
            short8v a0 = *(const short8v*)(xrow + (xofs + 0) * 32);
            short8v a1 = *(const short8v*)(xrow + (xofs + 1) * 32);
            short8v a2 = *(const short8v*)(xrow + (xofs + 2) * 32);
            short8v a3 = *(const short8v*)(xrow + (xofs + 3) * 32);
            ac0 = __builtin_amdgcn_mfma_f32_16x16x32_bf16(a0, bxr[0], ac0, 0, 0, 0);
            ac1 = __builtin_amdgcn_mfma_f32_16x16x32_bf16(a1, bxr[1], ac1, 0, 0, 0);
            ac2 = __builtin_amdgcn_mfma_f32_16x16x32_bf16(a2, bxr[2], ac2, 0, 0, 0);
            ac3 = __builtin_amdgcn_mfma_f32_16x16x32_bf16(a3, bxr[3], ac3, 0, 0, 0);
        }

        // spin until all blocks finished step t-1
        if (t > 0 && tid == 0) {
            const uint target = (uint)NBLK * (uint)t;
            while (__hip_atomic_load(bar, __ATOMIC_RELAXED, __HIP_MEMORY_SCOPE_AGENT) < target)
                __builtin_amdgcn_s_sleep(1);
        }
        __syncthreads();
        asm volatile("" ::: "memory");

        // h-part: 16 ksteps from registers bh[]
        #pragma unroll
        for (int i = 0; i < 16; i += 4) {
            short8v a0 = *(const short8v*)(hrow + (hofs + i + 0) * 32);
            short8v a1 = *(const short8v*)(hrow + (hofs + i + 1) * 32);
            short8v a2 = *(const short8v*)(hrow + (hofs + i + 2) * 32);
            short8v a3 = *(const short8v*)(hrow + (hofs + i + 3) * 32);
            ac0 = __builtin_amdgcn_mfma_f32_16x16x32_bf16(a0, bh[i + 0], ac0, 0, 0, 0);
            ac1 = __builtin_amdgcn_mfma_f32_16x16x32_bf16(a1, bh[i + 1], ac1, 0, 0, 0);
            ac2 = __builtin_amdgcn_mfma_f32_16x16x32_bf16(a2, bh[i + 2], ac2, 0, 0, 0);
            ac3 = __builtin_amdgcn_mfma_f32_16x16x32_bf16(a3, bh[i + 3], ac3, 0, 0, 0);
        }
        floatx4 acc = (ac0 + ac1) + (ac2 + ac3);

        // C/D layout: col = lane&15, row = (lane>>4)*4 + j
        #pragma unroll
        for (int j = 0; j < 4; ++j)
            pre[khalf][quad * 16 + (lane >> 4) * 4 + j][lane & 15] = acc[j];
        __syncthreads();

        // gate phase
        if (tid < 256) {
            float4 p0 = *(const float4*)&pre[0][gb][hl * 4];
            float4 p1 = *(const float4*)&pre[1][gb][hl * 4];
            float f  = sigm(p0.x + p1.x + bxf);
            float i_ = sigm(p0.y + p1.y + bxi);
            float o  = sigm(p0.z + p1.z + bxo);
            float a  = p0.w + p1.w + bxa;
            c_reg = i_ * tanh_fast(a) + f * c_reg;
            float h = o * tanh_fast(c_reg);
            ushort hv = f2bf(h);
            ushort* hp = hsteps + (size_t)(t + 1) * BH + gb * HID + gn;
            uint hvu = hv;
            asm volatile("global_store_short %0, %1, off sc0 sc1"
                         :: "v"(hp), "v"(hvu) : "memory");
        }
        __syncthreads();   // drains the sc1 stores (vmcnt) for all gate waves

        if (t < T - 1 && tid == 0)
            __hip_atomic_fetch_add(bar, 1u, __ATOMIC_RELAXED, __HIP_MEMORY_SCOPE_AGENT);
    }
}

// Output projection via MFMA: block (mtile, nt) computes rows m0..m0+63,
// cols nt*64..nt*64+63 (masked to 257). K = HID.
__global__ __launch_bounds__(256) void outproj(const ushort* __restrict__ hsb,
                                               const ushort* __restrict__ wof,
                                               const float* __restrict__ bo,
                                               float* __restrict__ out) {
    const int m0   = blockIdx.x * 64;
    const int nt   = blockIdx.y;          // 0..4
    const int tid  = threadIdx.x;
    const int w    = tid >> 6;
    const int lane = tid & 63;
    const int kg8  = (lane >> 4) * 8;
    const ushort* arow = hsb + (size_t)(m0 + w * 16 + (lane & 15)) * HID + kg8;
    const short8v* wb  = (const short8v*)wof;

    floatx4 ac[4] = {{0.f,0.f,0.f,0.f},{0.f,0.f,0.f,0.f},
                     {0.f,0.f,0.f,0.f},{0.f,0.f,0.f,0.f}};
    #pragma unroll 4
    for (int ks = 0; ks < 32; ++ks) {
        short8v av = *(const short8v*)(arow + ks * 32);
        #pragma unroll
        for (int ct = 0; ct < 4; ++ct)
            ac[ct] = __builtin_amdgcn_mfma_f32_16x16x32_bf16(
                av, wb[((nt * 4 + ct) * 32 + ks) * 64 + lane], ac[ct], 0, 0, 0);
    }
    const int orow = m0 + w * 16 + (lane >> 4) * 4;
    #pragma unroll
    for (int ct = 0; ct < 4; ++ct) {
        int n = nt * 64 + ct * 16 + (lane & 15);
        if (n < NCLS) {
            float bias = bo[n];
            #pragma unroll
            for (int j = 0; j < 4; ++j)
                out[(size_t)(orow + j) * NCLS + n] = ac[ct][j] + bias;
        }
    }
}

extern "C" void kernel_launch(void* const* d_in, const int* in_sizes, int n_in,
                              void* d_out, int out_size, void* d_ws, size_t ws_size,
                              hipStream_t stream) {
    const float* x  = (const float*)d_in[0];   // [T,B,FEAT]
    const float* Wx = (const float*)d_in[1];   // [4,4,64,256]
    const float* bx = (const float*)d_in[2];   // [4,HID]
    const float* Wh = (const float*)d_in[3];   // [4,4,256,256]
    const float* Wo = (const float*)d_in[4];   // [HID,NCLS]
    const float* bo = (const float*)d_in[5];   // [NCLS]
    float* out = (float*)d_out;

    // Workspace layout (ushort units), ~53.2 MB total
    ushort* xb     = (ushort*)d_ws;                        // 4,194,304
    ushort* wcf    = xb  + (size_t)T * B * FEAT;           // 5,242,880
    ushort* wof    = wcf + (size_t)KSTEPS * 256 * 512;     // 327,680
    ushort* hsteps = wof + 327680;                         // (T+1)*BH = 16,842,752
    uint*   bar    = (uint*)(hsteps + (size_t)(T + 1) * BH);

    conv_x<<<(T * B * FEAT / 4) / 256, 256, 0, stream>>>(x, xb);
    prep_wcf<<<(256 * KSTEPS * 512) / 256, 256, 0, stream>>>(Wh, Wx, wcf);
    prep_wof<<<(20 * 32 * 512) / 256, 256, 0, stream>>>(Wo, wof);
    init_hc<<<BH / 256, 256, 0, stream>>>(hsteps, bar);

    void* args[] = {(void*)&xb, (void*)&wcf, (void*)&bx, (void*)&hsteps, (void*)&bar};
    hipLaunchCooperativeKernel((void*)qlstm_persist, dim3(NBLK), dim3(NTHR),
                               args, 0, stream);

    outproj<<<dim3(T * B / 64, 5), 256, 0, stream>>>(hsteps + BH, wof, bo, out);
}

// Round 6
// 1753.090 us; speedup vs baseline: 11.9501x; 1.2386x over previous
//
#include <hip/hip_runtime.h>
#include <hip/hip_bf16.h>
#include <math.h>

// Problem constants
#define T 256
#define B 64
#define FEAT 256
#define HID 1024
#define NCLS 257
#define KSTEPS 40          // K = 1280 = 40 * 32
#define BH (B * HID)
#define NBLK 256
#define NTHR 512

typedef __attribute__((ext_vector_type(8))) short short8v;   // 8 x bf16
typedef __attribute__((ext_vector_type(4))) float floatx4;   // MFMA acc

// Hamilton block component/sign tables
__device__ __constant__ int   d_comp[4][4] = {{0,1,2,3},{1,0,3,2},{2,3,0,1},{3,2,1,0}};
__device__ __constant__ float d_sign[4][4] = {{ 1.f, 1.f, 1.f, 1.f},
                                              {-1.f, 1.f,-1.f, 1.f},
                                              {-1.f, 1.f, 1.f,-1.f},
                                              {-1.f,-1.f, 1.f, 1.f}};

__device__ __forceinline__ ushort f2bf(float f) {
    union { float f; unsigned u; } v; v.f = f;
    unsigned r = v.u + 0x7FFF + ((v.u >> 16) & 1);   // RNE
    return (ushort)(r >> 16);
}

__device__ __forceinline__ float sigm(float v) { return 1.f / (1.f + __expf(-v)); }
__device__ __forceinline__ float tanh_fast(float v) { return 1.f - 2.f / (1.f + __expf(2.f * v)); }

// x (fp32) -> xb (bf16), same [T][B][FEAT] layout
__global__ __launch_bounds__(256) void conv_x(const float* __restrict__ x,
                                              ushort* __restrict__ xb) {
    int i = blockIdx.x * 256 + threadIdx.x;   // over T*B*FEAT/4
    float4 v = ((const float4*)x)[i];
    ushort4 o;
    o.x = f2bf(v.x); o.y = f2bf(v.y); o.z = f2bf(v.z); o.w = f2bf(v.w);
    ((ushort4*)xb)[i] = o;
}

// Build frag-ordered bf16 combined weights:
// wcf element e = ((blk*40 + ks)*64 + lane)*8 + j
//   gate col c = lane&15 -> hl = c>>2, g = c&3; hidden col n = blk*4+hl
//   k = ks*32 + (lane>>4)*8 + j   (k<1024: Wh rows, else Wx rows)
__global__ __launch_bounds__(256) void prep_wcf(const float* __restrict__ Wh,
                                                const float* __restrict__ Wx,
                                                ushort* __restrict__ wcf) {
    int e = blockIdx.x * 256 + threadIdx.x;   // < 256*40*512 = 5,242,880
    int j    = e & 7;
    int lane = (e >> 3) & 63;
    int q40  = e >> 9;
    int blk  = q40 / 40;
    int ks   = q40 - blk * 40;
    int c  = lane & 15;
    int hl = c >> 2, g = c & 3;
    int n  = blk * 4 + hl;
    int qq = n >> 8, bc = n & 255;
    int k  = ks * 32 + ((lane >> 4) << 3) + j;
    float v;
    if (k < HID) {
        int p = k >> 8, a = k & 255;
        v = d_sign[p][qq] * Wh[((g * 4 + d_comp[p][qq]) * 256 + a) * 256 + bc];
    } else {
        int kk = k - HID;
        int p = kk >> 6, a = kk & 63;
        v = d_sign[p][qq] * Wx[((g * 4 + d_comp[p][qq]) * 64 + a) * 256 + bc];
    }
    wcf[e] = f2bf(v);
}

// Wo -> frag-ordered bf16, cols padded to 320
__global__ __launch_bounds__(256) void prep_wof(const float* __restrict__ Wo,
                                                ushort* __restrict__ wof) {
    int e = blockIdx.x * 256 + threadIdx.x;   // < 20*32*512 = 327,680
    int j    = e & 7;
    int lane = (e >> 3) & 63;
    int ks   = (e >> 9) & 31;
    int tile = e >> 14;
    int n = tile * 16 + (lane & 15);
    int k = ks * 32 + ((lane >> 4) << 3) + j;
    wof[e] = (n < NCLS) ? f2bf(Wo[k * NCLS + n]) : (ushort)0;
}

// zero h slot 0 and the flag array
__global__ __launch_bounds__(256) void init_hc(ushort* __restrict__ hs0,
                                               uint* __restrict__ flags) {
    int i = blockIdx.x * 256 + threadIdx.x;   // over BH
    hs0[i] = 0;
    if (i < NBLK) flags[i] = 0;
}

// Persistent kernel: all 256 LSTM steps, flag-array barrier (no RMW, no fences).
// Block blk owns hidden cols blk*4..blk*4+3 (16 gate cols). 8 waves:
// khalf = w>>2 splits K, quad = w&3 -> batch rows quad*16..+15.
// All 20 B-fragments pinned in registers for the whole sequence.
__global__ __launch_bounds__(512, 2) void qlstm_persist(
    const ushort* __restrict__ xb,     // [T][B][FEAT] bf16
    const ushort* __restrict__ wcf,    // frag-ordered weights
    const float*  __restrict__ bx,     // [4][1024]
    ushort*       __restrict__ hsteps, // [T+1][B][HID] bf16 (slot s = h after s steps)
    uint*         __restrict__ flags)  // [NBLK] per-block step flags
{
    __shared__ float pre[2][64][20];

    const int tid   = threadIdx.x;
    const int blk   = blockIdx.x;
    const int w     = tid >> 6;
    const int lane  = tid & 63;
    const int khalf = w >> 2;
    const int quad  = w & 3;
    const int rowoff  = (quad * 16 + (lane & 15)) * HID + (lane >> 4) * 8;
    const int xrowoff = (quad * 16 + (lane & 15)) * FEAT + (lane >> 4) * 8;
    const int hofs  = khalf * 16;   // h ksteps: 0..15 or 16..31
    const int xofs  = khalf * 4;    // x ksteps (local): 0..3 or 4..7

    // ---- one-time: B-fragments -> registers, pinned via asm barrier ----
    const short8v* wsrc = (const short8v*)(wcf + (size_t)blk * KSTEPS * 512);
    short8v bh[16], bxr[4];
    #pragma unroll
    for (int i = 0; i < 16; ++i) bh[i] = wsrc[(hofs + i) * 64 + lane];
    #pragma unroll
    for (int u = 0; u < 4; ++u)  bxr[u] = wsrc[(32 + xofs + u) * 64 + lane];
    #pragma unroll
    for (int i = 0; i < 16; ++i) asm volatile("" : "+v"(bh[i]));
    #pragma unroll
    for (int u = 0; u < 4; ++u)  asm volatile("" : "+v"(bxr[u]));

    // ---- gate-phase identity (threads 0..255): (b, hl) ----
    const int gb = tid >> 2;
    const int hl = tid & 3;
    const int gn = blk * 4 + hl;
    float bxf = 0.f, bxi = 0.f, bxo = 0.f, bxa = 0.f;
    if (tid < 256) {
        bxf = bx[gn]; bxi = bx[HID + gn];
        bxo = bx[2 * HID + gn]; bxa = bx[3 * HID + gn];
    }
    float c_reg = 0.f;

    for (int t = 0; t < T; ++t) {
        const ushort* hrow = hsteps + (size_t)t * BH + rowoff;
        const ushort* xrow = xb + (size_t)t * (B * FEAT) + xrowoff;

        floatx4 ac0 = {0.f,0.f,0.f,0.f}, ac1 = {0.f,0.f,0.f,0.f};
        floatx4 ac2 = {0.f,0.f,0.f,0.f}, ac3 = {0.f,0.f,0.f,0.f};

        // x-part (independent of this step's h) — overlaps barrier wait
        {
            short8v a0 = *(const short8v*)(xrow + (xofs + 0) * 32);
            short8v a1 = *(const short8v*)(xrow + (xofs + 1) * 32);
            short8v a2 = *(const short8v*)(xrow + (xofs + 2) * 32);
            short8v a3 = *(const short8v*)(xrow + (xofs + 3) * 32);
            ac0 = __builtin_amdgcn_mfma_f32_16x16x32_bf16(a0, bxr[0], ac0, 0, 0, 0);
            ac1 = __builtin_amdgcn_mfma_f32_16x16x32_bf16(a1, bxr[1], ac1, 0, 0, 0);
            ac2 = __builtin_amdgcn_mfma_f32_16x16x32_bf16(a2, bxr[2], ac2, 0, 0, 0);
            ac3 = __builtin_amdgcn_mfma_f32_16x16x32_bf16(a3, bxr[3], ac3, 0, 0, 0);
        }

        // barrier: wave 0 polls all 256 flags (4 per lane), no RMW anywhere
        if (t > 0) {
            if (w == 0) {
                const uint tgt = (uint)t;
                for (;;) {
                    uint f0 = __hip_atomic_load(flags + lane,       __ATOMIC_RELAXED, __HIP_MEMORY_SCOPE_AGENT);
                    uint f1 = __hip_atomic_load(flags + 64 + lane,  __ATOMIC_RELAXED, __HIP_MEMORY_SCOPE_AGENT);
                    uint f2 = __hip_atomic_load(flags + 128 + lane, __ATOMIC_RELAXED, __HIP_MEMORY_SCOPE_AGENT);
                    uint f3 = __hip_atomic_load(flags + 192 + lane, __ATOMIC_RELAXED, __HIP_MEMORY_SCOPE_AGENT);
                    bool ok = (f0 >= tgt) && (f1 >= tgt) && (f2 >= tgt) && (f3 >= tgt);
                    if (__all(ok)) break;
                    __builtin_amdgcn_s_sleep(1);
                }
            }
            __syncthreads();
        }

        // h-part: 16 ksteps, weights from pinned registers
        #pragma unroll
        for (int i = 0; i < 16; i += 4) {
            short8v a0 = *(const short8v*)(hrow + (hofs + i + 0) * 32);
            short8v a1 = *(const short8v*)(hrow + (hofs + i + 1) * 32);
            short8v a2 = *(const short8v*)(hrow + (hofs + i + 2) * 32);
            short8v a3 = *(const short8v*)(hrow + (hofs + i + 3) * 32);
            ac0 = __builtin_amdgcn_mfma_f32_16x16x32_bf16(a0, bh[i + 0], ac0, 0, 0, 0);
            ac1 = __builtin_amdgcn_mfma_f32_16x16x32_bf16(a1, bh[i + 1], ac1, 0, 0, 0);
            ac2 = __builtin_amdgcn_mfma_f32_16x16x32_bf16(a2, bh[i + 2], ac2, 0, 0, 0);
            ac3 = __builtin_amdgcn_mfma_f32_16x16x32_bf16(a3, bh[i + 3], ac3, 0, 0, 0);
        }
        floatx4 acc = (ac0 + ac1) + (ac2 + ac3);

        // C/D layout: col = lane&15, row = (lane>>4)*4 + j
        #pragma unroll
        for (int j = 0; j < 4; ++j)
            pre[khalf][quad * 16 + (lane >> 4) * 4 + j][lane & 15] = acc[j];
        __syncthreads();

        // gate phase
        if (tid < 256) {
            float4 p0 = *(const float4*)&pre[0][gb][hl * 4];
            float4 p1 = *(const float4*)&pre[1][gb][hl * 4];
            float f  = sigm(p0.x + p1.x + bxf);
            float i_ = sigm(p0.y + p1.y + bxi);
            float o  = sigm(p0.z + p1.z + bxo);
            float a  = p0.w + p1.w + bxa;
            c_reg = i_ * tanh_fast(a) + f * c_reg;
            float h = o * tanh_fast(c_reg);
            ushort hv = f2bf(h);
            ushort* hp = hsteps + (size_t)(t + 1) * BH + gb * HID + gn;
            uint hvu = hv;
            asm volatile("global_store_short %0, %1, off sc0 sc1"
                         :: "v"(hp), "v"(hvu) : "memory");
            asm volatile("s_waitcnt vmcnt(0)" ::: "memory");
        }
        __syncthreads();   // all h stores of this block are drained & visible

        if (t < T - 1 && tid == 0)
            __hip_atomic_store(flags + blk, (uint)(t + 1),
                               __ATOMIC_RELAXED, __HIP_MEMORY_SCOPE_AGENT);
    }
}

// Output projection via MFMA: block (mtile, nt) computes rows m0..m0+63,
// cols nt*64..nt*64+63 (masked to 257). K = HID.
__global__ __launch_bounds__(256) void outproj(const ushort* __restrict__ hsb,
                                               const ushort* __restrict__ wof,
                                               const float* __restrict__ bo,
                                               float* __restrict__ out) {
    const int m0   = blockIdx.x * 64;
    const int nt   = blockIdx.y;          // 0..4
    const int tid  = threadIdx.x;
    const int w    = tid >> 6;
    const int lane = tid & 63;
    const int kg8  = (lane >> 4) * 8;
    const ushort* arow = hsb + (size_t)(m0 + w * 16 + (lane & 15)) * HID + kg8;
    const short8v* wb  = (const short8v*)wof;

    floatx4 ac[4] = {{0.f,0.f,0.f,0.f},{0.f,0.f,0.f,0.f},
                     {0.f,0.f,0.f,0.f},{0.f,0.f,0.f,0.f}};
    #pragma unroll 4
    for (int ks = 0; ks < 32; ++ks) {
        short8v av = *(const short8v*)(arow + ks * 32);
        #pragma unroll
        for (int ct = 0; ct < 4; ++ct)
            ac[ct] = __builtin_amdgcn_mfma_f32_16x16x32_bf16(
                av, wb[((nt * 4 + ct) * 32 + ks) * 64 + lane], ac[ct], 0, 0, 0);
    }
    const int orow = m0 + w * 16 + (lane >> 4) * 4;
    #pragma unroll
    for (int ct = 0; ct < 4; ++ct) {
        int n = nt * 64 + ct * 16 + (lane & 15);
        if (n < NCLS) {
            float bias = bo[n];
            #pragma unroll
            for (int j = 0; j < 4; ++j)
                out[(size_t)(orow + j) * NCLS + n] = ac[ct][j] + bias;
        }
    }
}

extern "C" void kernel_launch(void* const* d_in, const int* in_sizes, int n_in,
                              void* d_out, int out_size, void* d_ws, size_t ws_size,
                              hipStream_t stream) {
    const float* x  = (const float*)d_in[0];   // [T,B,FEAT]
    const float* Wx = (const float*)d_in[1];   // [4,4,64,256]
    const float* bx = (const float*)d_in[2];   // [4,HID]
    const float* Wh = (const float*)d_in[3];   // [4,4,256,256]
    const float* Wo = (const float*)d_in[4];   // [HID,NCLS]
    const float* bo = (const float*)d_in[5];   // [NCLS]
    float* out = (float*)d_out;

    // Workspace layout (ushort units), ~53.2 MB total
    ushort* xb     = (ushort*)d_ws;                        // 4,194,304
    ushort* wcf    = xb  + (size_t)T * B * FEAT;           // 5,242,880
    ushort* wof    = wcf + (size_t)KSTEPS * 256 * 512;     // 327,680
    ushort* hsteps = wof + 327680;                         // (T+1)*BH = 16,842,752
    uint*   flags  = (uint*)(hsteps + (size_t)(T + 1) * BH);

    conv_x<<<(T * B * FEAT / 4) / 256, 256, 0, stream>>>(x, xb);
    prep_wcf<<<(256 * KSTEPS * 512) / 256, 256, 0, stream>>>(Wh, Wx, wcf);
    prep_wof<<<(20 * 32 * 512) / 256, 256, 0, stream>>>(Wo, wof);
    init_hc<<<BH / 256, 256, 0, stream>>>(hsteps, flags);

    void* args[] = {(void*)&xb, (void*)&wcf, (void*)&bx, (void*)&hsteps, (void*)&flags};
    hipLaunchCooperativeKernel((void*)qlstm_persist, dim3(NBLK), dim3(NTHR),
                               args, 0, stream);

    outproj<<<dim3(T * B / 64, 5), 256, 0, stream>>>(hsteps + BH, wof, bo, out);
}

// Round 7
// 1100.752 us; speedup vs baseline: 19.0320x; 1.5926x over previous
//
#include <hip/hip_runtime.h>
#include <hip/hip_bf16.h>
#include <math.h>

// Problem constants
#define T 256
#define B 64
#define FEAT 256
#define HID 1024
#define NCLS 257
#define KSTEPS 40          // K = 1280 = 40 * 32
#define BH (B * HID)
#define BFEAT (B * FEAT)
#define NBLK 128           // 1 block per 8 hidden columns
#define NTHR 512

typedef __attribute__((ext_vector_type(8))) short short8v;   // 8 x bf16
typedef __attribute__((ext_vector_type(4))) float floatx4;   // MFMA acc

// Hamilton block component/sign tables
__device__ __constant__ int   d_comp[4][4] = {{0,1,2,3},{1,0,3,2},{2,3,0,1},{3,2,1,0}};
__device__ __constant__ float d_sign[4][4] = {{ 1.f, 1.f, 1.f, 1.f},
                                              {-1.f, 1.f,-1.f, 1.f},
                                              {-1.f, 1.f, 1.f,-1.f},
                                              {-1.f,-1.f, 1.f, 1.f}};

__device__ __forceinline__ ushort f2bf(float f) {
    union { float f; unsigned u; } v; v.f = f;
    unsigned r = v.u + 0x7FFF + ((v.u >> 16) & 1);   // RNE
    return (ushort)(r >> 16);
}

__device__ __forceinline__ float sigm(float v) { return 1.f / (1.f + __expf(-v)); }
__device__ __forceinline__ float tanh_fast(float v) { return 1.f - 2.f / (1.f + __expf(2.f * v)); }

// x (fp32 [T][B][FEAT]) -> panel-layout bf16 xpanel[T][FEAT/8][B][8]
__global__ __launch_bounds__(256) void conv_xpanel(const float* __restrict__ x,
                                                   ushort* __restrict__ xp) {
    int i = blockIdx.x * 256 + threadIdx.x;   // over T*B*FEAT/4
    int k4 = i & 63, b = (i >> 6) & 63, t = i >> 12;
    int k = k4 * 4;
    float4 v = ((const float4*)x)[i];
    ushort4 o;
    o.x = f2bf(v.x); o.y = f2bf(v.y); o.z = f2bf(v.z); o.w = f2bf(v.w);
    *(ushort4*)(xp + (size_t)t * BFEAT + (k >> 3) * 512 + b * 8 + (k & 4)) = o;
}

// Build frag-ordered bf16 weights for the SWAPPED orientation (A = W^T):
// e = (((blk*2+mt)*40 + ks)*64 + lane)*8 + j
//   gate col c = mt*16 + (lane&15); hl = c>>2, g = c&3; hidden col n = blk*8+hl
//   k = ks*32 + (lane>>4)*8 + j   (k<1024: Wh rows, else Wx rows)
__global__ __launch_bounds__(256) void prep_wcf(const float* __restrict__ Wh,
                                                const float* __restrict__ Wx,
                                                ushort* __restrict__ wcf) {
    int e = blockIdx.x * 256 + threadIdx.x;   // < 128*2*40*512 = 5,242,880
    int j    = e & 7;
    int lane = (e >> 3) & 63;
    int r    = e >> 9;
    int ks   = r % 40;
    int s    = r / 40;
    int mt   = s & 1;
    int blk  = s >> 1;
    int c  = mt * 16 + (lane & 15);
    int hl = c >> 2, g = c & 3;
    int n  = blk * 8 + hl;
    int qq = n >> 8, bc = n & 255;
    int k  = ks * 32 + ((lane >> 4) << 3) + j;
    float v;
    if (k < HID) {
        int p = k >> 8, a = k & 255;
        v = d_sign[p][qq] * Wh[((g * 4 + d_comp[p][qq]) * 256 + a) * 256 + bc];
    } else {
        int kk = k - HID;
        int p = kk >> 6, a = kk & 63;
        v = d_sign[p][qq] * Wx[((g * 4 + d_comp[p][qq]) * 64 + a) * 256 + bc];
    }
    wcf[e] = f2bf(v);
}

// Wo -> frag-ordered bf16, cols padded to 320 (unchanged orientation: A = h)
__global__ __launch_bounds__(256) void prep_wof(const float* __restrict__ Wo,
                                                ushort* __restrict__ wof) {
    int e = blockIdx.x * 256 + threadIdx.x;   // < 20*32*512 = 327,680
    int j    = e & 7;
    int lane = (e >> 3) & 63;
    int ks   = (e >> 9) & 31;
    int tile = e >> 14;
    int n = tile * 16 + (lane & 15);
    int k = ks * 32 + ((lane >> 4) << 3) + j;
    wof[e] = (n < NCLS) ? f2bf(Wo[k * NCLS + n]) : (ushort)0;
}

// zero h slot 0 and the flag array
__global__ __launch_bounds__(256) void init_hc(ushort* __restrict__ hs0,
                                               uint* __restrict__ flags) {
    int i = blockIdx.x * 256 + threadIdx.x;   // over BH
    hs0[i] = 0;
    if (i < NBLK) flags[i] = 0;
}

// Persistent kernel: all 256 LSTM steps. Block blk owns hidden cols
// blk*8..blk*8+7 (32 gate cols = 2 m-tiles). 8 waves: (khalf = w>>2, bt = w&3).
// h lives in panel layout [slot][HID/8][B][8]: full-line coalesced stores AND
// coalesced 16B B-frag loads. Gates fully in-thread (1 thread = 1 (b,hidcol)).
__global__ __launch_bounds__(512, 2) void qlstm_persist(
    const ushort* __restrict__ xp,     // [T][FEAT/8][B][8] bf16
    const ushort* __restrict__ wcf,    // frag-ordered weights (A = W^T)
    const float*  __restrict__ bx,     // [4][1024]
    ushort*       __restrict__ hsteps, // [T+1][HID/8][B][8] bf16
    uint*         __restrict__ flags)  // [NBLK] per-block step flags
{
    __shared__ float pre[2][64][36];   // [khalf][batch][gatecol(32), pad 36]

    const int tid   = threadIdx.x;
    const int blk   = blockIdx.x;
    const int w     = tid >> 6;
    const int lane  = tid & 63;
    const int khalf = w >> 2;
    const int bt    = w & 3;
    const int hofs  = khalf * 16;   // h ksteps 0..15 / 16..31
    const int xofs  = khalf * 4;    // x ksteps (local) 0..3 / 4..7

    // ---- one-time: A-fragments (W^T) -> registers, pinned ----
    const short8v* wsrc = (const short8v*)wcf + (size_t)blk * 2 * KSTEPS * 64 + lane;
    short8v Ah[2][16], Ax[2][4];
    #pragma unroll
    for (int mt = 0; mt < 2; ++mt) {
        #pragma unroll
        for (int i = 0; i < 16; ++i) Ah[mt][i] = wsrc[(mt * KSTEPS + hofs + i) * 64];
        #pragma unroll
        for (int u = 0; u < 4; ++u)  Ax[mt][u] = wsrc[(mt * KSTEPS + 32 + xofs + u) * 64];
    }
    #pragma unroll
    for (int mt = 0; mt < 2; ++mt) {
        #pragma unroll
        for (int i = 0; i < 16; ++i) asm volatile("" : "+v"(Ah[mt][i]));
        #pragma unroll
        for (int u = 0; u < 4; ++u)  asm volatile("" : "+v"(Ax[mt][u]));
    }

    // ---- gate identity: thread -> (gb = batch, hc = hidden-local) ----
    const int gb = tid >> 3;
    const int hc = tid & 7;
    const int gn = blk * 8 + hc;
    const float bxf = bx[gn], bxi = bx[HID + gn];
    const float bxo = bx[2 * HID + gn], bxa = bx[3 * HID + gn];
    float c_reg = 0.f;

    // B-frag lane offset (shorts): (panel-row lane>>4)*512 + batch*8
    const int boff = (lane >> 4) * 512 + (bt * 16 + (lane & 15)) * 8;

    for (int t = 0; t < T; ++t) {
        floatx4 acc0 = {0.f,0.f,0.f,0.f}, acc1 = {0.f,0.f,0.f,0.f};

        // x-part (independent of h_t) — before the barrier
        const ushort* xrow = xp + (size_t)t * BFEAT + boff;
        #pragma unroll
        for (int u = 0; u < 4; ++u) {
            short8v bv = *(const short8v*)(xrow + (xofs + u) * 2048);
            acc0 = __builtin_amdgcn_mfma_f32_16x16x32_bf16(Ax[0][u], bv, acc0, 0, 0, 0);
            acc1 = __builtin_amdgcn_mfma_f32_16x16x32_bf16(Ax[1][u], bv, acc1, 0, 0, 0);
        }

        // barrier: every wave polls all 128 flags (2 per lane)
        if (t > 0) {
            const uint tgt = (uint)t;
            for (;;) {
                uint f0 = __hip_atomic_load(flags + lane,      __ATOMIC_RELAXED, __HIP_MEMORY_SCOPE_AGENT);
                uint f1 = __hip_atomic_load(flags + 64 + lane, __ATOMIC_RELAXED, __HIP_MEMORY_SCOPE_AGENT);
                if (__all((f0 >= tgt) && (f1 >= tgt))) break;
                __builtin_amdgcn_s_sleep(1);
            }
        }

        // h-part: 16 coalesced 16B B-frag loads from panel layout
        const ushort* hrow = hsteps + (size_t)t * BH + boff;
        #pragma unroll
        for (int i = 0; i < 16; ++i) {
            short8v bv = *(const short8v*)(hrow + (hofs + i) * 2048);
            acc0 = __builtin_amdgcn_mfma_f32_16x16x32_bf16(Ah[0][i], bv, acc0, 0, 0, 0);
            acc1 = __builtin_amdgcn_mfma_f32_16x16x32_bf16(Ah[1][i], bv, acc1, 0, 0, 0);
        }

        // D layout: n(batch) = lane&15, m(gatecol-in-tile) = (lane>>4)*4 + jj
        {
            const int pb = bt * 16 + (lane & 15);
            const int pm = (lane >> 4) * 4;
            #pragma unroll
            for (int jj = 0; jj < 4; ++jj) {
                pre[khalf][pb][pm + jj]      = acc0[jj];
                pre[khalf][pb][16 + pm + jj] = acc1[jj];
            }
        }
        __syncthreads();

        // gates: in-thread, c in register
        {
            float4 p0 = *(const float4*)&pre[0][gb][hc * 4];
            float4 p1 = *(const float4*)&pre[1][gb][hc * 4];
            float f  = sigm(p0.x + p1.x + bxf);
            float i_ = sigm(p0.y + p1.y + bxi);
            float o  = sigm(p0.z + p1.z + bxo);
            float a  = p0.w + p1.w + bxa;
            c_reg = i_ * tanh_fast(a) + f * c_reg;
            float h = o * tanh_fast(c_reg);
            uint hvu = f2bf(h);
            ushort* hp = hsteps + (size_t)(t + 1) * BH + blk * 512 + tid;
            asm volatile("global_store_short %0, %1, off sc0 sc1"
                         :: "v"(hp), "v"(hvu) : "memory");
            asm volatile("s_waitcnt vmcnt(0)" ::: "memory");
        }
        __syncthreads();   // all full-line h stores of this block drained

        if (t < T - 1 && tid == 0)
            __hip_atomic_store(flags + blk, (uint)(t + 1),
                               __ATOMIC_RELAXED, __HIP_MEMORY_SCOPE_AGENT);
    }
}

// Output projection via MFMA: block (t, nt): rows t*64..t*64+63 (one t),
// cols nt*64..+63 masked to 257. A-frags read h from panel layout.
__global__ __launch_bounds__(256) void outproj(const ushort* __restrict__ hsteps,
                                               const ushort* __restrict__ wof,
                                               const float* __restrict__ bo,
                                               float* __restrict__ out) {
    const int tt   = blockIdx.x;          // 0..255 (= t)
    const int nt   = blockIdx.y;          // 0..4
    const int tid  = threadIdx.x;
    const int w    = tid >> 6;
    const int lane = tid & 63;
    const int b    = w * 16 + (lane & 15);
    const ushort* abase = hsteps + (size_t)(tt + 1) * BH + (lane >> 4) * 512 + b * 8;
    const short8v* wb  = (const short8v*)wof;

    floatx4 ac[4] = {{0.f,0.f,0.f,0.f},{0.f,0.f,0.f,0.f},
                     {0.f,0.f,0.f,0.f},{0.f,0.f,0.f,0.f}};
    #pragma unroll 4
    for (int ks = 0; ks < 32; ++ks) {
        short8v av = *(const short8v*)(abase + ks * 2048);
        #pragma unroll
        for (int ct = 0; ct < 4; ++ct)
            ac[ct] = __builtin_amdgcn_mfma_f32_16x16x32_bf16(
                av, wb[((nt * 4 + ct) * 32 + ks) * 64 + lane], ac[ct], 0, 0, 0);
    }
    const int orow = tt * 64 + w * 16 + (lane >> 4) * 4;
    #pragma unroll
    for (int ct = 0; ct < 4; ++ct) {
        int n = nt * 64 + ct * 16 + (lane & 15);
        if (n < NCLS) {
            float bias = bo[n];
            #pragma unroll
            for (int j = 0; j < 4; ++j)
                out[(size_t)(orow + j) * NCLS + n] = ac[ct][j] + bias;
        }
    }
}

extern "C" void kernel_launch(void* const* d_in, const int* in_sizes, int n_in,
                              void* d_out, int out_size, void* d_ws, size_t ws_size,
                              hipStream_t stream) {
    const float* x  = (const float*)d_in[0];   // [T,B,FEAT]
    const float* Wx = (const float*)d_in[1];   // [4,4,64,256]
    const float* bx = (const float*)d_in[2];   // [4,HID]
    const float* Wh = (const float*)d_in[3];   // [4,4,256,256]
    const float* Wo = (const float*)d_in[4];   // [HID,NCLS]
    const float* bo = (const float*)d_in[5];   // [NCLS]
    float* out = (float*)d_out;

    // Workspace layout (ushort units), ~53.2 MB total
    ushort* xp     = (ushort*)d_ws;                        // 4,194,304
    ushort* wcf    = xp  + (size_t)T * BFEAT;              // 5,242,880
    ushort* wof    = wcf + (size_t)NBLK * 2 * KSTEPS * 512;// 327,680
    ushort* hsteps = wof + 327680;                         // (T+1)*BH = 16,842,752
    uint*   flags  = (uint*)(hsteps + (size_t)(T + 1) * BH);

    conv_xpanel<<<(T * B * FEAT / 4) / 256, 256, 0, stream>>>(x, xp);
    prep_wcf<<<(NBLK * 2 * KSTEPS * 512) / 256, 256, 0, stream>>>(Wh, Wx, wcf);
    prep_wof<<<(20 * 32 * 512) / 256, 256, 0, stream>>>(Wo, wof);
    init_hc<<<BH / 256, 256, 0, stream>>>(hsteps, flags);

    void* args[] = {(void*)&xp, (void*)&wcf, (void*)&bx, (void*)&hsteps, (void*)&flags};
    hipLaunchCooperativeKernel((void*)qlstm_persist, dim3(NBLK), dim3(NTHR),
                               args, 0, stream);

    outproj<<<dim3(T, 5), 256, 0, stream>>>(hsteps, wof, bo, out);
}